// Round 1
// baseline (60.077 us; speedup 1.0000x reference)
//
#include <hip/hip_runtime.h>

// EdgeOrientation2mer: B=2, N=2048, K=48, A=4 atoms/node.
// out[b,n,k, a*24 + bb*3 + y] = mask * dot(p[bb]-p[a], n_{y+1}) * rsqrt(|d|^2 + 0.1)
// where p[0..3] = X[b,n,:,:], p[4..7] = X[b,edge_idx[b,n,k],:,:],
// frame n1,n2,n3 from atoms 0(N),1(CA),2(C) of node i.

constexpr int Bq = 2, Nq = 2048, Kq = 48;
constexpr float EPS = 0.1f;

struct F3 { float x, y, z; };
__device__ __forceinline__ F3 f3sub(F3 a, F3 b) { return {a.x - b.x, a.y - b.y, a.z - b.z}; }
__device__ __forceinline__ float f3dot(F3 a, F3 b) { return a.x * b.x + a.y * b.y + a.z * b.z; }
__device__ __forceinline__ F3 f3scale(F3 a, float s) { return {a.x * s, a.y * s, a.z * s}; }
__device__ __forceinline__ F3 f3normed(F3 v) {
    float inv = rsqrtf(f3dot(v, v) + EPS);
    return f3scale(v, inv);
}
__device__ __forceinline__ F3 f3cross(F3 a, F3 b) {
    return {a.y * b.z - a.z * b.y, a.z * b.x - a.x * b.z, a.x * b.y - a.y * b.x};
}

__global__ __launch_bounds__(256) void edge_orient_kernel(
    const float* __restrict__ X,   // [B,N,4,3]
    const int* __restrict__ E,     // [B,N,K]
    const int* __restrict__ C,     // [B,N]
    float* __restrict__ out)       // [B,N,K,192]
{
    const int gid = blockIdx.x * 4 + (threadIdx.x >> 6);   // edge index
    const int lane = threadIdx.x & 63;                     // pair index
    const int total = Bq * Nq * Kq;
    if (gid >= total) return;

    const int b = gid / (Nq * Kq);
    const int rem = gid - b * (Nq * Kq);
    const int n = rem / Kq;
    const int node = b * Nq + n;
    const int idx = E[gid];
    const int nodej = b * Nq + idx;

    const float m = (C[node] > 0 && C[nodej] > 0) ? 1.0f : 0.0f;

    const float* Xi = X + node * 12;
    const float* Xj = X + nodej * 12;

    // Local frame from node i atoms 0,1,2 (N, CA, C)
    F3 XN  = {Xi[0], Xi[1], Xi[2]};
    F3 XCA = {Xi[3], Xi[4], Xi[5]};
    F3 XC  = {Xi[6], Xi[7], Xi[8]};
    F3 n1 = f3normed(f3sub(XN, XCA));
    F3 uC = f3normed(f3sub(XC, XCA));
    F3 n2 = f3normed(f3cross(n1, uC));
    F3 n3 = f3normed(f3cross(n1, n2));

    // This lane's atom pair: U[a][bb] = p[bb] - p[a]
    const int a  = lane >> 3;
    const int bb = lane & 7;
    const float* pap = (a  < 4) ? (Xi + a * 3)  : (Xj + (a - 4) * 3);
    const float* pbp = (bb < 4) ? (Xi + bb * 3) : (Xj + (bb - 4) * 3);
    F3 pa = {pap[0], pap[1], pap[2]};
    F3 pb = {pbp[0], pbp[1], pbp[2]};

    F3 d = f3sub(pb, pa);
    const float inv = rsqrtf(f3dot(d, d) + EPS) * m;

    float* op = out + (size_t)gid * 192 + lane * 3;
    op[0] = f3dot(d, n1) * inv;
    op[1] = f3dot(d, n2) * inv;
    op[2] = f3dot(d, n3) * inv;
}

extern "C" void kernel_launch(void* const* d_in, const int* in_sizes, int n_in,
                              void* d_out, int out_size, void* d_ws, size_t ws_size,
                              hipStream_t stream) {
    const float* X = (const float*)d_in[0];
    const int*   E = (const int*)d_in[1];
    const int*   C = (const int*)d_in[2];
    float* out = (float*)d_out;

    const int total = Bq * Nq * Kq;           // 196608 edges, one wave each
    dim3 block(256);                          // 4 waves/block
    dim3 grid(total / 4);                     // exact
    edge_orient_kernel<<<grid, block, 0, stream>>>(X, E, C, out);
}

// Round 2
// 51.989 us; speedup vs baseline: 1.1556x; 1.1556x over previous
//
#include <hip/hip_runtime.h>

// EdgeOrientation2mer v2: thread = (edge, row a). Each thread computes the 8
// pairs (a, b=0..7) of its edge and writes 24 contiguous floats (6x float4).
// B=2, N=2048, K=48, A=4 atoms/node. out[b,n,k, a*24 + b2*3 + y].

constexpr int Bq = 2, Nq = 2048, Kq = 48;
constexpr float EPS = 0.1f;

struct F3 { float x, y, z; };
__device__ __forceinline__ F3 f3sub(F3 a, F3 b) { return {a.x - b.x, a.y - b.y, a.z - b.z}; }
__device__ __forceinline__ float f3dot(F3 a, F3 b) {
    return fmaf(a.x, b.x, fmaf(a.y, b.y, a.z * b.z));
}
__device__ __forceinline__ F3 f3scale(F3 a, float s) { return {a.x * s, a.y * s, a.z * s}; }
__device__ __forceinline__ F3 f3normed(F3 v) {
    float inv = rsqrtf(f3dot(v, v) + EPS);
    return f3scale(v, inv);
}
__device__ __forceinline__ F3 f3cross(F3 a, F3 b) {
    return {a.y * b.z - a.z * b.y, a.z * b.x - a.x * b.z, a.x * b.y - a.y * b.x};
}

__global__ __launch_bounds__(256) void edge_orient_rows_kernel(
    const float* __restrict__ X,   // [B,N,4,3]
    const int* __restrict__ E,     // [B,N,K]
    const int* __restrict__ C,     // [B,N]
    float* __restrict__ out)       // [B,N,K,192]
{
    const unsigned tid = blockIdx.x * 256u + threadIdx.x;
    const unsigned edge = tid >> 3;        // [0, 196608)
    const unsigned a = tid & 7u;           // row (first pair index)

    const unsigned node = edge / (unsigned)Kq;     // = b*N + n (linear)
    const unsigned bidx = node >> 11;              // batch
    const int j = E[edge];
    const unsigned nodej = (bidx << 11) + (unsigned)j;

    const float m = (C[node] > 0 && C[nodej] > 0) ? 1.0f : 0.0f;

    // All 8 atoms of the edge, statically unpacked (vector loads, 16B aligned).
    const float4* Xi4 = reinterpret_cast<const float4*>(X + (size_t)node * 12);
    const float4* Xj4 = reinterpret_cast<const float4*>(X + (size_t)nodej * 12);
    const float4 A0 = Xi4[0], A1 = Xi4[1], A2 = Xi4[2];
    const float4 B0 = Xj4[0], B1 = Xj4[1], B2 = Xj4[2];

    const F3 p0 = {A0.x, A0.y, A0.z};   // i atom 0 (N)
    const F3 p1 = {A0.w, A1.x, A1.y};   // i atom 1 (CA)
    const F3 p2 = {A1.z, A1.w, A2.x};   // i atom 2 (C)
    const F3 p3 = {A2.y, A2.z, A2.w};   // i atom 3
    const F3 p4 = {B0.x, B0.y, B0.z};   // j atoms
    const F3 p5 = {B0.w, B1.x, B1.y};
    const F3 p6 = {B1.z, B1.w, B2.x};
    const F3 p7 = {B2.y, B2.z, B2.w};

    // Local frame of node i (atoms N, CA, C); fold mask into the frame vectors.
    const F3 n1u = f3normed(f3sub(p0, p1));
    const F3 uC  = f3normed(f3sub(p2, p1));
    const F3 n2u = f3normed(f3cross(n1u, uC));
    const F3 n3u = f3normed(f3cross(n1u, n2u));
    const F3 n1 = f3scale(n1u, m), n2 = f3scale(n2u, m), n3 = f3scale(n3u, m);

    // This row's atom a: load directly (avoids runtime-indexed register array).
    const float* pap = X + (size_t)(a < 4u ? node : nodej) * 12 + (a & 3u) * 3;
    const F3 pa = {pap[0], pap[1], pap[2]};

    float o[24];
#pragma unroll
    for (int b2 = 0; b2 < 8; ++b2) {
        F3 pb;
        switch (b2) {   // static after unroll
            case 0: pb = p0; break; case 1: pb = p1; break;
            case 2: pb = p2; break; case 3: pb = p3; break;
            case 4: pb = p4; break; case 5: pb = p5; break;
            case 6: pb = p6; break; default: pb = p7; break;
        }
        const F3 d = f3sub(pb, pa);
        const float nn = fmaf(d.x, d.x, fmaf(d.y, d.y, fmaf(d.z, d.z, EPS)));
        const float inv = rsqrtf(nn);
        o[b2 * 3 + 0] = f3dot(d, n1) * inv;
        o[b2 * 3 + 1] = f3dot(d, n2) * inv;
        o[b2 * 3 + 2] = f3dot(d, n3) * inv;
    }

    float4* ob = reinterpret_cast<float4*>(out + (size_t)edge * 192 + a * 24);
    ob[0] = make_float4(o[0],  o[1],  o[2],  o[3]);
    ob[1] = make_float4(o[4],  o[5],  o[6],  o[7]);
    ob[2] = make_float4(o[8],  o[9],  o[10], o[11]);
    ob[3] = make_float4(o[12], o[13], o[14], o[15]);
    ob[4] = make_float4(o[16], o[17], o[18], o[19]);
    ob[5] = make_float4(o[20], o[21], o[22], o[23]);
}

extern "C" void kernel_launch(void* const* d_in, const int* in_sizes, int n_in,
                              void* d_out, int out_size, void* d_ws, size_t ws_size,
                              hipStream_t stream) {
    const float* X = (const float*)d_in[0];
    const int*   E = (const int*)d_in[1];
    const int*   C = (const int*)d_in[2];
    float* out = (float*)d_out;

    const int total_threads = Bq * Nq * Kq * 8;   // 1,572,864
    dim3 block(256);
    dim3 grid(total_threads / 256);               // 6144, exact
    edge_orient_rows_kernel<<<grid, block, 0, stream>>>(X, E, C, out);
}

// Round 3
// 29.468 us; speedup vs baseline: 2.0387x; 1.7643x over previous
//
#include <hip/hip_runtime.h>

// EdgeOrientation2mer v3: v2 compute + LDS-staged coalesced stores.
// Block = 256 threads = 32 edges (8 threads/edge, thread = one row a).
// Phase 1: compute 24 floats, stage to LDS (XOR-swizzled, conflict-free).
// Phase 2: block writes its 24 KB output span with lane-contiguous float4.

constexpr int Bq = 2, Nq = 2048, Kq = 48;
constexpr float EPS = 0.1f;

struct F3 { float x, y, z; };
__device__ __forceinline__ F3 f3sub(F3 a, F3 b) { return {a.x - b.x, a.y - b.y, a.z - b.z}; }
__device__ __forceinline__ float f3dot(F3 a, F3 b) {
    return fmaf(a.x, b.x, fmaf(a.y, b.y, a.z * b.z));
}
__device__ __forceinline__ F3 f3scale(F3 a, float s) { return {a.x * s, a.y * s, a.z * s}; }
__device__ __forceinline__ F3 f3normed(F3 v) {
    float inv = rsqrtf(f3dot(v, v) + EPS);
    return f3scale(v, inv);
}
__device__ __forceinline__ F3 f3cross(F3 a, F3 b) {
    return {a.y * b.z - a.z * b.y, a.z * b.x - a.x * b.z, a.x * b.y - a.y * b.x};
}

__global__ __launch_bounds__(256) void edge_orient_v3_kernel(
    const float* __restrict__ X,   // [B,N,4,3]
    const int* __restrict__ E,     // [B,N,K]
    const int* __restrict__ C,     // [B,N]
    float* __restrict__ out)       // [B,N,K,192]
{
    __shared__ float4 smem[2048];           // 32 KB: 256 threads x 8 f4 slots

    const int t = threadIdx.x;
    const unsigned edge = blockIdx.x * 32u + (unsigned)(t >> 3);
    const unsigned a = t & 7u;

    const unsigned node = edge / (unsigned)Kq;     // = b*N + n (linear)
    const unsigned bidx = node >> 11;              // batch
    const int j = E[edge];
    const unsigned nodej = (bidx << 11) + (unsigned)j;

    const float m = (C[node] > 0 && C[nodej] > 0) ? 1.0f : 0.0f;

    const float4* Xi4 = reinterpret_cast<const float4*>(X + (size_t)node * 12);
    const float4* Xj4 = reinterpret_cast<const float4*>(X + (size_t)nodej * 12);
    const float4 A0 = Xi4[0], A1 = Xi4[1], A2 = Xi4[2];
    const float4 B0 = Xj4[0], B1 = Xj4[1], B2 = Xj4[2];

    const F3 p0 = {A0.x, A0.y, A0.z};
    const F3 p1 = {A0.w, A1.x, A1.y};
    const F3 p2 = {A1.z, A1.w, A2.x};
    const F3 p3 = {A2.y, A2.z, A2.w};
    const F3 p4 = {B0.x, B0.y, B0.z};
    const F3 p5 = {B0.w, B1.x, B1.y};
    const F3 p6 = {B1.z, B1.w, B2.x};
    const F3 p7 = {B2.y, B2.z, B2.w};

    // Local frame of node i; fold mask into the frame vectors.
    const F3 n1u = f3normed(f3sub(p0, p1));
    const F3 uC  = f3normed(f3sub(p2, p1));
    const F3 n2u = f3normed(f3cross(n1u, uC));
    const F3 n3u = f3normed(f3cross(n1u, n2u));
    const F3 n1 = f3scale(n1u, m), n2 = f3scale(n2u, m), n3 = f3scale(n3u, m);

    // This row's atom a (direct load avoids runtime-indexed register array).
    const float* pap = X + (size_t)(a < 4u ? node : nodej) * 12 + (a & 3u) * 3;
    const F3 pa = {pap[0], pap[1], pap[2]};

    float o[24] __attribute__((aligned(16)));
#pragma unroll
    for (int b2 = 0; b2 < 8; ++b2) {
        F3 pb;
        switch (b2) {
            case 0: pb = p0; break; case 1: pb = p1; break;
            case 2: pb = p2; break; case 3: pb = p3; break;
            case 4: pb = p4; break; case 5: pb = p5; break;
            case 6: pb = p6; break; default: pb = p7; break;
        }
        const F3 d = f3sub(pb, pa);
        const float nn = fmaf(d.x, d.x, fmaf(d.y, d.y, fmaf(d.z, d.z, EPS)));
        const float inv = rsqrtf(nn);
        o[b2 * 3 + 0] = f3dot(d, n1) * inv;
        o[b2 * 3 + 1] = f3dot(d, n2) * inv;
        o[b2 * 3 + 2] = f3dot(d, n3) * inv;
    }

    // Stage to LDS. Thread t's logical f4 i (i=0..5) -> phys t*8 + (i ^ (t&7)).
    // Per instruction i: bank color = i ^ (t&7) covers all 8 colors twice per
    // 16-lane quarter -> 2 lanes/bank = conflict-free.
    const float4* ov = reinterpret_cast<const float4*>(o);
#pragma unroll
    for (int i = 0; i < 6; ++i) {
        smem[t * 8 + (i ^ (t & 7))] = ov[i];
    }
    __syncthreads();

    // Coalesced writeback: block's 1536 f4 span, lane-contiguous.
    float4* outb = reinterpret_cast<float4*>(out) + (size_t)blockIdx.x * 1536;
#pragma unroll
    for (int s = 0; s < 6; ++s) {
        const unsigned g4 = (unsigned)s * 256u + (unsigned)t;   // logical f4
        const unsigned o4 = g4 / 6u;                            // owner thread
        const unsigned i4 = g4 - o4 * 6u;                       // owner's f4 idx
        outb[g4] = smem[o4 * 8u + (i4 ^ (o4 & 7u))];
    }
}

extern "C" void kernel_launch(void* const* d_in, const int* in_sizes, int n_in,
                              void* d_out, int out_size, void* d_ws, size_t ws_size,
                              hipStream_t stream) {
    const float* X = (const float*)d_in[0];
    const int*   E = (const int*)d_in[1];
    const int*   C = (const int*)d_in[2];
    float* out = (float*)d_out;

    const int total_edges = Bq * Nq * Kq;     // 196,608
    dim3 block(256);
    dim3 grid(total_edges / 32);              // 6144 blocks, exact
    edge_orient_v3_kernel<<<grid, block, 0, stream>>>(X, E, C, out);
}